// Round 29
// baseline (198.121 us; speedup 1.0000x reference)
//
#include <hip/hip_runtime.h>

#define DEVI __device__ __forceinline__

typedef __attribute__((ext_vector_type(8))) short bh8;    // 8 x bf16 (as raw shorts)
typedef __attribute__((ext_vector_type(4))) float f32x4;

static constexpr int Bsz  = 4;
static constexpr int Lseq = 2048;
static constexpr int INDIM = 1024;
static constexpr int NH = 16;
static constexpr int HD = 64;
static constexpr int QKVN = 3 * NH * HD;   // 3072
static constexpr int OUTD = 1024;
static constexpr int Mrows = Bsz * Lseq;   // 8192

DEVI unsigned short f2bf(float f) {
    unsigned u = __float_as_uint(f);
    u = u + 0x7fffu + ((u >> 16) & 1u);      // RNE
    return (unsigned short)(u >> 16);
}

// async global->LDS, 16 bytes per lane (HW: wave-uniform LDS base + lane*16)
DEVI void gl2lds16(const unsigned short* g, unsigned short* l) {
    __builtin_amdgcn_global_load_lds(
        (const __attribute__((address_space(1))) void*)g,
        (__attribute__((address_space(3))) void*)l, 16, 0, 0);
}

// ---------------------------------------------------------------- fused prep
// One dispatch: [0,4096) convert X f32->bf16; [4096,4864) transpose Wqkv;
// [4864,5120) transpose Wout. (R27-verified: -4.1us vs 3 dispatches.)
static constexpr int CV_BLKS = Mrows * INDIM / 8 / 256;           // 4096
static constexpr int TQ_BLKS = (QKVN / 64) * (INDIM / 64);        // 768
static constexpr int TO_BLKS = (OUTD / 64) * ((NH * HD) / 64);    // 256

__global__ __launch_bounds__(256) void prep_fused(
    const float* __restrict__ X, unsigned short* __restrict__ Xb,
    const float* __restrict__ Wqkv, unsigned short* __restrict__ WqkvT,
    const float* __restrict__ Wout, unsigned short* __restrict__ WoutT) {
    __shared__ unsigned short t[64][65];
    int bid = blockIdx.x, tid = threadIdx.x;
    if (bid < CV_BLKS) {                      // ---- convert (vectorized 8/thread)
        int i = bid * 256 + tid;
        const f32x4* p = (const f32x4*)(X + (size_t)i * 8);
        f32x4 a = p[0], b = p[1];
        bh8 o;
        o[0] = (short)f2bf(a[0]); o[1] = (short)f2bf(a[1]);
        o[2] = (short)f2bf(a[2]); o[3] = (short)f2bf(a[3]);
        o[4] = (short)f2bf(b[0]); o[5] = (short)f2bf(b[1]);
        o[6] = (short)f2bf(b[2]); o[7] = (short)f2bf(b[3]);
        *(bh8*)(Xb + (size_t)i * 8) = o;
        return;
    }
    const float* W; unsigned short* Wt; int K, N, n0, k0;
    if (bid < CV_BLKS + TQ_BLKS) {            // ---- transpose Wqkv [K][N]->[N][K]
        int tb = bid - CV_BLKS;
        K = INDIM; N = QKVN;
        n0 = (tb % (QKVN / 64)) * 64; k0 = (tb / (QKVN / 64)) * 64;
        W = Wqkv; Wt = WqkvT;
    } else {                                  // ---- transpose Wout
        int tb = bid - CV_BLKS - TQ_BLKS;
        K = NH * HD; N = OUTD;
        n0 = (tb % (OUTD / 64)) * 64; k0 = (tb / (OUTD / 64)) * 64;
        W = Wout; Wt = WoutT;
    }
#pragma unroll
    for (int i = 0; i < 16; ++i) {
        int idx = tid + i * 256;
        int r = idx >> 6, c = idx & 63;
        t[r][c] = f2bf(W[(size_t)(k0 + r) * N + (n0 + c)]);
    }
    __syncthreads();
#pragma unroll
    for (int i = 0; i < 16; ++i) {
        int idx = tid + i * 256;
        int r = idx >> 6, c = idx & 63;
        Wt[(size_t)(n0 + r) * K + (k0 + c)] = t[c][r];
    }
}

// ---------------------------------------------------------------- GEMM C = A * Bt^T
// (R23/R28-verified: 2-phase dbuf + T1 chunked XCD swizzle + BK=64 + T2
// source-side XOR swizzle, conflicts 0.)
// MODE 0: scatter to Q (pre-scaled 1/8) / K [B*H][L][64], Vt [B*H][64][L].
template <int MODE>
__global__ __launch_bounds__(256) void gemm_bt(
    const unsigned short* __restrict__ A, const unsigned short* __restrict__ Bt,
    float* __restrict__ Cf, unsigned short* __restrict__ Qg,
    unsigned short* __restrict__ Kg, unsigned short* __restrict__ Vg,
    int K, int ntn, int cpx) {
    __shared__ unsigned short Al[2][128 * 64];   // 2 x 16 KB, 128B rows, swizzled
    __shared__ unsigned short Bl[2][128 * 64];
    int tid = threadIdx.x;
    int lane = tid & 63, wave = tid >> 6;
    int bid = blockIdx.x;
    int swz = (bid & 7) * cpx + (bid >> 3);   // T1: XCD gets contiguous chunk
    int mt = swz / ntn, nt_ = swz % ntn;
    int m0 = mt * 128, n0 = nt_ * 128;
    int wm = (wave >> 1) * 64, wn = (wave & 1) * 64;

    int srow = tid >> 3;
    int scol = ((tid & 7) ^ (srow & 7)) * 8;
    const unsigned short* Ags = A + (size_t)(m0 + srow) * K + scol;
    const unsigned short* Bgs = Bt + (size_t)(n0 + srow) * K + scol;
    int wofs = wave * 512;                    // wave covers 8 rows (1KB)

    f32x4 acc[4][4] = {};
    int cl = lane & 15, kq = (lane >> 4) * 8;

    int nt = K >> 6;                          // K/64 tiles (16 for K=1024)
    auto stage = [&](int t, int buf) {        // 8 issues: 4 A + 4 B (32 rows ea)
        int kof = t * 64;
#pragma unroll
        for (int i = 0; i < 4; ++i) {
            gl2lds16(Ags + (size_t)(32 * i) * K + kof, &Al[buf][0] + 32 * i * 64 + wofs);
            gl2lds16(Bgs + (size_t)(32 * i) * K + kof, &Bl[buf][0] + 32 * i * 64 + wofs);
        }
    };

    stage(0, 0);
    __syncthreads();

    int cur = 0;
    for (int t = 0; t < nt; ++t) {
        if (t + 1 < nt) stage(t + 1, cur ^ 1);
        bh8 af[4][2], bf[4][2];
#pragma unroll
        for (int mi = 0; mi < 4; ++mi) {
            int ar = wm + mi * 16 + cl, as = (ar & 7) << 3;
#pragma unroll
            for (int ks = 0; ks < 2; ++ks)
                af[mi][ks] = *(const bh8*)(&Al[cur][0] + ar * 64 + ((ks * 32 + kq) ^ as));
        }
#pragma unroll
        for (int nj = 0; nj < 4; ++nj) {
            int br = wn + nj * 16 + cl, bs = (br & 7) << 3;
#pragma unroll
            for (int ks = 0; ks < 2; ++ks)
                bf[nj][ks] = *(const bh8*)(&Bl[cur][0] + br * 64 + ((ks * 32 + kq) ^ bs));
        }
#pragma unroll
        for (int ks = 0; ks < 2; ++ks)
#pragma unroll
            for (int mi = 0; mi < 4; ++mi)
#pragma unroll
                for (int nj = 0; nj < 4; ++nj)
                    acc[mi][nj] = __builtin_amdgcn_mfma_f32_16x16x32_bf16(
                        af[mi][ks], bf[nj][ks], acc[mi][nj], 0, 0, 0);
        if (t + 1 < nt) __syncthreads();      // drains vmcnt (t+1 landed) + lgkm
        cur ^= 1;
    }

    int rb = (lane >> 4) * 4;
#pragma unroll
    for (int mi = 0; mi < 4; ++mi) {
#pragma unroll
        for (int nj = 0; nj < 4; ++nj) {
#pragma unroll
            for (int r = 0; r < 4; ++r) {
                int gm = m0 + wm + mi * 16 + rb + r;
                int gn = n0 + wn + nj * 16 + cl;
                float v = acc[mi][nj][r];
                if (MODE == 0) {
                    int b = gm >> 11, ls = gm & 2047;
                    int sel = gn >> 10, h = (gn >> 6) & 15, d = gn & 63;
                    if (sel == 0)   // Q pre-scaled by 1/sqrt(HD) (exact exp shift)
                        Qg[((size_t)(b * NH + h) * Lseq + ls) * HD + d] = f2bf(v * 0.125f);
                    else if (sel == 1)
                        Kg[((size_t)(b * NH + h) * Lseq + ls) * HD + d] = f2bf(v);
                    else  // V transposed: Vt[bh][d][kv]
                        Vg[((size_t)(b * NH + h) * HD + d) * Lseq + ls] = f2bf(v);
                } else {
                    Cf[(size_t)gm * OUTD + gn] = v;
                }
            }
        }
    }
}

// ---------------------------------------------------------------- causal flash attention
// R28 body + K/V LDS DOUBLE-BUFFER, single barrier per iter: issue loads(j+1)
// -> compute(j) from buf[cur] (load latency hides under MFMA+exp) -> ds_write
// into buf[cur^1] (disjoint buffer: no pre-write barrier; vmcnt waits after
// compute ~0 stall) -> one barrier. Race: iter j writes b_{j+1}; last reader
// was iter j-1 whose reads finished before its end-barrier; iter j+1 reads
// after j's barrier. P tile unpadded [16][64] with col-group XOR swizzle
// col ^= (row&7)<<3 (write scalar / read bh8; banks 8-group 2-way = free).
// LDS 16+16+8 = 40KB -> exactly 4 blocks/CU.
__global__ __launch_bounds__(256) void attn_causal(
    const unsigned short* __restrict__ Qg, const unsigned short* __restrict__ Kg,
    const unsigned short* __restrict__ Vt, unsigned short* __restrict__ Og) {
    __shared__ unsigned short Kl[2][64 * 64];     // 16 KB, row-swizzled, dbuf
    __shared__ unsigned short Vl[2][64 * 64];     // 16 KB
    __shared__ unsigned short Pl[4][16 * 64];     // 8 KB, col-group swizzled
    int tid = threadIdx.x, wave = tid >> 6, lane = tid & 63;
    int bid = blockIdx.x;
    int xcd = bid & 7, slot = bid >> 3;       // slot 0..127
    int p = slot & 15;                        // pair index 0..15
    int bh = ((slot >> 4) << 3) | xcd;        // bh in 0..63, bh%8==xcd
    int b = bh >> 4, h = bh & 15;
    const unsigned short* Qp = Qg + (size_t)bh * Lseq * HD;
    const unsigned short* Kp = Kg + (size_t)bh * Lseq * HD;
    const unsigned short* Vp = Vt + (size_t)bh * HD * Lseq;   // [d][kv]
    int cl = lane & 15, kq = (lane >> 4) * 8, rb = (lane >> 4) * 4;
    unsigned short* Pw = &Pl[wave][0];
    int psw = (cl & 7) << 3;                  // P read-side col-group swizzle

    int srow = tid >> 2;                      // staging row 0..63
    int sc0 = (tid & 3) * 16;                 // element chunk base
    int ssw = (srow & 7) << 3;                // K/V write-side swizzle (elements)

    bh8 ones;
#pragma unroll
    for (int i = 0; i < 8; ++i) ones[i] = (short)0x3F80;   // bf16 1.0

    for (int pass = 0; pass < 2; ++pass) {
        int pt = pass ? (31 - p) : p;
        int q0 = pt * 64 + wave * 16;         // this wave's 16 rows

        bh8 qf0 = *(const bh8*)(Qp + (size_t)(q0 + cl) * HD + kq);
        bh8 qf1 = *(const bh8*)(Qp + (size_t)(q0 + cl) * HD + 32 + kq);

        f32x4 o[4] = {};
        f32x4 osum = {};                      // P row-sums via ones-MFMA

        int nblk = pt + 1;                    // uniform across waves
        // prologue: stage kv-block 0 into buf 0
        {
            const unsigned short* Ks = Kp + (size_t)srow * HD;
            const unsigned short* Vs = Vp + (size_t)srow * Lseq;
            bh8 k0 = *(const bh8*)(Ks + sc0);
            bh8 k1 = *(const bh8*)(Ks + sc0 + 8);
            bh8 v0 = *(const bh8*)(Vs + sc0);
            bh8 v1 = *(const bh8*)(Vs + sc0 + 8);
            __syncthreads();                  // prior pass's buf reads done
            *(bh8*)(&Kl[0][0] + srow * 64 + (sc0 ^ ssw)) = k0;
            *(bh8*)(&Kl[0][0] + srow * 64 + ((sc0 + 8) ^ ssw)) = k1;
            *(bh8*)(&Vl[0][0] + srow * 64 + (sc0 ^ ssw)) = v0;
            *(bh8*)(&Vl[0][0] + srow * 64 + ((sc0 + 8) ^ ssw)) = v1;
            __syncthreads();
        }
        int cur = 0;
        for (int j = 0; j < nblk; ++j) {
            int kv0 = j * 64;
            bool masked = (j == nblk - 1);    // only diagonal block needs mask
            bool pre = (j + 1 < nblk);
            bh8 k0, k1, v0, v1;
            if (pre) {                        // issue next-block loads NOW
                int kn = kv0 + 64;
                const unsigned short* Ks = Kp + (size_t)(kn + srow) * HD;
                const unsigned short* Vs = Vp + (size_t)srow * Lseq + kn;
                k0 = *(const bh8*)(Ks + sc0);
                k1 = *(const bh8*)(Ks + sc0 + 8);
                v0 = *(const bh8*)(Vs + sc0);
                v1 = *(const bh8*)(Vs + sc0 + 8);
            }
            __builtin_amdgcn_s_setprio(1);    // T5: compute region priority
            const unsigned short* Kc = &Kl[cur][0];
            const unsigned short* Vc = &Vl[cur][0];
            // ---- QK^T from LDS (loads in flight underneath)
#pragma unroll
            for (int nb = 0; nb < 4; ++nb) {
                int row = nb * 16 + cl, rs = (row & 7) << 3;
                bh8 kf0 = *(const bh8*)(Kc + row * 64 + (kq ^ rs));
                bh8 kf1 = *(const bh8*)(Kc + row * 64 + ((kq + 32) ^ rs));
                f32x4 s = {};
                s = __builtin_amdgcn_mfma_f32_16x16x32_bf16(qf0, kf0, s, 0, 0, 0);
                s = __builtin_amdgcn_mfma_f32_16x16x32_bf16(qf1, kf1, s, 0, 0, 0);
                if (masked) {                 // wave-uniform branch
                    int col = kv0 + nb * 16 + cl;
#pragma unroll
                    for (int r = 0; r < 4; ++r) {
                        float v = s[r];                   // Q pre-scaled by 1/8
                        if (col > q0 + rb + r) v = -3e30f;
                        int rr = rb + r;
                        Pw[rr * 64 + ((nb * 16 + cl) ^ ((rr & 7) << 3))] = f2bf(__expf(v));
                    }
                } else {
#pragma unroll
                    for (int r = 0; r < 4; ++r) {
                        int rr = rb + r;
                        Pw[rr * 64 + ((nb * 16 + cl) ^ ((rr & 7) << 3))] = f2bf(__expf(s[r]));
                    }
                }
            }
            // ---- P·V from LDS
            bh8 pa0 = *(const bh8*)(Pw + cl * 64 + (kq ^ psw));
            bh8 pa1 = *(const bh8*)(Pw + cl * 64 + ((32 + kq) ^ psw));
#pragma unroll
            for (int db = 0; db < 4; ++db) {
                int dr = db * 16 + cl, ds = (dr & 7) << 3;
                bh8 vf0 = *(const bh8*)(Vc + dr * 64 + (kq ^ ds));
                bh8 vf1 = *(const bh8*)(Vc + dr * 64 + ((kq + 32) ^ ds));
                o[db] = __builtin_amdgcn_mfma_f32_16x16x32_bf16(pa0, vf0, o[db], 0, 0, 0);
                o[db] = __builtin_amdgcn_mfma_f32_16x16x32_bf16(pa1, vf1, o[db], 0, 0, 0);
            }
            osum = __builtin_amdgcn_mfma_f32_16x16x32_bf16(pa0, ones, osum, 0, 0, 0);
            osum = __builtin_amdgcn_mfma_f32_16x16x32_bf16(pa1, ones, osum, 0, 0, 0);
            __builtin_amdgcn_s_setprio(0);    // back to staging priority
            if (pre) {                        // write next block into other buf
                *(bh8*)(&Kl[cur ^ 1][0] + srow * 64 + (sc0 ^ ssw)) = k0;
                *(bh8*)(&Kl[cur ^ 1][0] + srow * 64 + ((sc0 + 8) ^ ssw)) = k1;
                *(bh8*)(&Vl[cur ^ 1][0] + srow * 64 + (sc0 ^ ssw)) = v0;
                *(bh8*)(&Vl[cur ^ 1][0] + srow * 64 + ((sc0 + 8) ^ ssw)) = v1;
            }
            __syncthreads();                  // single barrier per iteration
            cur ^= 1;
        }
#pragma unroll
        for (int r = 0; r < 4; ++r) {
            float inv = 1.0f / osum[r];
            int row = q0 + rb + r;
            size_t obase = (size_t)(b * Lseq + row) * OUTD + h * HD;
#pragma unroll
            for (int db = 0; db < 4; ++db)
                Og[obase + db * 16 + cl] = f2bf(o[db][r] * inv);
        }
    }
}

// ---------------------------------------------------------------- launch
extern "C" void kernel_launch(void* const* d_in, const int* in_sizes, int n_in,
                              void* d_out, int out_size, void* d_ws, size_t ws_size,
                              hipStream_t stream) {
    (void)in_sizes; (void)n_in; (void)out_size; (void)ws_size;
    const float* X    = (const float*)d_in[0];
    const float* Wqkv = (const float*)d_in[1];
    const float* Wout = (const float*)d_in[2];
    float* out = (float*)d_out;

    char* ws = (char*)d_ws;
    size_t off = 0;
    unsigned short* Xb    = (unsigned short*)(ws + off); off += (size_t)Mrows * INDIM * 2;
    unsigned short* WqkvT = (unsigned short*)(ws + off); off += (size_t)QKVN * INDIM * 2;
    unsigned short* WoutT = (unsigned short*)(ws + off); off += (size_t)OUTD * (NH * HD) * 2;
    unsigned short* Qg    = (unsigned short*)(ws + off); off += (size_t)Mrows * NH * HD * 2;
    unsigned short* Kg    = (unsigned short*)(ws + off); off += (size_t)Mrows * NH * HD * 2;
    unsigned short* Vtg   = (unsigned short*)(ws + off); off += (size_t)Mrows * NH * HD * 2;
    unsigned short* Ob    = (unsigned short*)(ws + off); off += (size_t)Mrows * NH * HD * 2;

    prep_fused<<<CV_BLKS + TQ_BLKS + TO_BLKS, 256, 0, stream>>>(
        X, Xb, Wqkv, WqkvT, Wout, WoutT);
    gemm_bt<0><<<(Mrows / 128) * (QKVN / 128), 256, 0, stream>>>(
        Xb, WqkvT, nullptr, Qg, Kg, Vtg, INDIM, QKVN / 128,
        (Mrows / 128) * (QKVN / 128) / 8);
    attn_causal<<<Bsz * NH * 16, 256, 0, stream>>>(Qg, Kg, Vtg, Ob);
    gemm_bt<1><<<(Mrows / 128) * (OUTD / 128), 256, 0, stream>>>(
        Ob, WoutT, out, nullptr, nullptr, nullptr, NH * HD, OUTD / 128,
        (Mrows / 128) * (OUTD / 128) / 8);
}

// Round 30
// 189.673 us; speedup vs baseline: 1.0445x; 1.0445x over previous
//
#include <hip/hip_runtime.h>

#define DEVI __device__ __forceinline__

typedef __attribute__((ext_vector_type(8))) short bh8;    // 8 x bf16 (as raw shorts)
typedef __attribute__((ext_vector_type(4))) float f32x4;

static constexpr int Bsz  = 4;
static constexpr int Lseq = 2048;
static constexpr int INDIM = 1024;
static constexpr int NH = 16;
static constexpr int HD = 64;
static constexpr int QKVN = 3 * NH * HD;   // 3072
static constexpr int OUTD = 1024;
static constexpr int Mrows = Bsz * Lseq;   // 8192

DEVI unsigned short f2bf(float f) {
    unsigned u = __float_as_uint(f);
    u = u + 0x7fffu + ((u >> 16) & 1u);      // RNE
    return (unsigned short)(u >> 16);
}

// async global->LDS, 16 bytes per lane (HW: wave-uniform LDS base + lane*16)
DEVI void gl2lds16(const unsigned short* g, unsigned short* l) {
    __builtin_amdgcn_global_load_lds(
        (const __attribute__((address_space(1))) void*)g,
        (__attribute__((address_space(3))) void*)l, 16, 0, 0);
}

// ---------------------------------------------------------------- fused prep
// One dispatch: [0,4096) convert X f32->bf16; [4096,4864) transpose Wqkv;
// [4864,5120) transpose Wout. (R27-verified: -4.1us vs 3 dispatches.)
static constexpr int CV_BLKS = Mrows * INDIM / 8 / 256;           // 4096
static constexpr int TQ_BLKS = (QKVN / 64) * (INDIM / 64);        // 768
static constexpr int TO_BLKS = (OUTD / 64) * ((NH * HD) / 64);    // 256

__global__ __launch_bounds__(256) void prep_fused(
    const float* __restrict__ X, unsigned short* __restrict__ Xb,
    const float* __restrict__ Wqkv, unsigned short* __restrict__ WqkvT,
    const float* __restrict__ Wout, unsigned short* __restrict__ WoutT) {
    __shared__ unsigned short t[64][65];
    int bid = blockIdx.x, tid = threadIdx.x;
    if (bid < CV_BLKS) {                      // ---- convert (vectorized 8/thread)
        int i = bid * 256 + tid;
        const f32x4* p = (const f32x4*)(X + (size_t)i * 8);
        f32x4 a = p[0], b = p[1];
        bh8 o;
        o[0] = (short)f2bf(a[0]); o[1] = (short)f2bf(a[1]);
        o[2] = (short)f2bf(a[2]); o[3] = (short)f2bf(a[3]);
        o[4] = (short)f2bf(b[0]); o[5] = (short)f2bf(b[1]);
        o[6] = (short)f2bf(b[2]); o[7] = (short)f2bf(b[3]);
        *(bh8*)(Xb + (size_t)i * 8) = o;
        return;
    }
    const float* W; unsigned short* Wt; int K, N, n0, k0;
    if (bid < CV_BLKS + TQ_BLKS) {            // ---- transpose Wqkv [K][N]->[N][K]
        int tb = bid - CV_BLKS;
        K = INDIM; N = QKVN;
        n0 = (tb % (QKVN / 64)) * 64; k0 = (tb / (QKVN / 64)) * 64;
        W = Wqkv; Wt = WqkvT;
    } else {                                  // ---- transpose Wout
        int tb = bid - CV_BLKS - TQ_BLKS;
        K = NH * HD; N = OUTD;
        n0 = (tb % (OUTD / 64)) * 64; k0 = (tb / (OUTD / 64)) * 64;
        W = Wout; Wt = WoutT;
    }
#pragma unroll
    for (int i = 0; i < 16; ++i) {
        int idx = tid + i * 256;
        int r = idx >> 6, c = idx & 63;
        t[r][c] = f2bf(W[(size_t)(k0 + r) * N + (n0 + c)]);
    }
    __syncthreads();
#pragma unroll
    for (int i = 0; i < 16; ++i) {
        int idx = tid + i * 256;
        int r = idx >> 6, c = idx & 63;
        Wt[(size_t)(n0 + r) * K + (k0 + c)] = t[c][r];
    }
}

// ---------------------------------------------------------------- GEMM C = A * Bt^T
// 2-phase dbuf (R14) + T1 chunked XCD swizzle (R22) + BK=64 (half the barriers,
// 2x MFMA per iter) + T2 source-side XOR swizzle (R16-verified mechanism):
// linear DMA dest, global source chunk ^= row&7, reads col ^= (row&7)<<3 ->
// 128B LDS rows read conflict-free. Accumulation order bit-identical to BK=32.
// MODE 0: scatter to Q (pre-scaled 1/8) / K [B*H][L][64], Vt [B*H][64][L].
template <int MODE>
__global__ __launch_bounds__(256) void gemm_bt(
    const unsigned short* __restrict__ A, const unsigned short* __restrict__ Bt,
    float* __restrict__ Cf, unsigned short* __restrict__ Qg,
    unsigned short* __restrict__ Kg, unsigned short* __restrict__ Vg,
    int K, int ntn, int cpx) {
    __shared__ unsigned short Al[2][128 * 64];   // 2 x 16 KB, 128B rows, swizzled
    __shared__ unsigned short Bl[2][128 * 64];
    int tid = threadIdx.x;
    int lane = tid & 63, wave = tid >> 6;
    int bid = blockIdx.x;
    int swz = (bid & 7) * cpx + (bid >> 3);   // T1: XCD gets contiguous chunk
    int mt = swz / ntn, nt_ = swz % ntn;
    int m0 = mt * 128, n0 = nt_ * 128;
    int wm = (wave >> 1) * 64, wn = (wave & 1) * 64;

    // staging: srow=tid>>3 covers 32 rows/issue; source chunk inverse-swizzled
    // so LDS[row][c] = global[row][c ^ ((row&7)*8)]
    int srow = tid >> 3;
    int scol = ((tid & 7) ^ (srow & 7)) * 8;
    const unsigned short* Ags = A + (size_t)(m0 + srow) * K + scol;
    const unsigned short* Bgs = Bt + (size_t)(n0 + srow) * K + scol;
    int wofs = wave * 512;                    // wave covers 8 rows (1KB)

    f32x4 acc[4][4] = {};
    int cl = lane & 15, kq = (lane >> 4) * 8;

    int nt = K >> 6;                          // K/64 tiles (16 for K=1024)
    auto stage = [&](int t, int buf) {        // 8 issues: 4 A + 4 B (32 rows ea)
        int kof = t * 64;
#pragma unroll
        for (int i = 0; i < 4; ++i) {
            gl2lds16(Ags + (size_t)(32 * i) * K + kof, &Al[buf][0] + 32 * i * 64 + wofs);
            gl2lds16(Bgs + (size_t)(32 * i) * K + kof, &Bl[buf][0] + 32 * i * 64 + wofs);
        }
    };

    stage(0, 0);
    __syncthreads();

    int cur = 0;
    for (int t = 0; t < nt; ++t) {
        if (t + 1 < nt) stage(t + 1, cur ^ 1);
        bh8 af[4][2], bf[4][2];
#pragma unroll
        for (int mi = 0; mi < 4; ++mi) {
            int ar = wm + mi * 16 + cl, as = (ar & 7) << 3;
#pragma unroll
            for (int ks = 0; ks < 2; ++ks)
                af[mi][ks] = *(const bh8*)(&Al[cur][0] + ar * 64 + ((ks * 32 + kq) ^ as));
        }
#pragma unroll
        for (int nj = 0; nj < 4; ++nj) {
            int br = wn + nj * 16 + cl, bs = (br & 7) << 3;
#pragma unroll
            for (int ks = 0; ks < 2; ++ks)
                bf[nj][ks] = *(const bh8*)(&Bl[cur][0] + br * 64 + ((ks * 32 + kq) ^ bs));
        }
#pragma unroll
        for (int ks = 0; ks < 2; ++ks)
#pragma unroll
            for (int mi = 0; mi < 4; ++mi)
#pragma unroll
                for (int nj = 0; nj < 4; ++nj)
                    acc[mi][nj] = __builtin_amdgcn_mfma_f32_16x16x32_bf16(
                        af[mi][ks], bf[nj][ks], acc[mi][nj], 0, 0, 0);
        if (t + 1 < nt) __syncthreads();      // drains vmcnt (t+1 landed) + lgkm
        cur ^= 1;
    }

    int rb = (lane >> 4) * 4;
#pragma unroll
    for (int mi = 0; mi < 4; ++mi) {
#pragma unroll
        for (int nj = 0; nj < 4; ++nj) {
#pragma unroll
            for (int r = 0; r < 4; ++r) {
                int gm = m0 + wm + mi * 16 + rb + r;
                int gn = n0 + wn + nj * 16 + cl;
                float v = acc[mi][nj][r];
                if (MODE == 0) {
                    int b = gm >> 11, ls = gm & 2047;
                    int sel = gn >> 10, h = (gn >> 6) & 15, d = gn & 63;
                    if (sel == 0)   // Q pre-scaled by 1/sqrt(HD) (exact exp shift)
                        Qg[((size_t)(b * NH + h) * Lseq + ls) * HD + d] = f2bf(v * 0.125f);
                    else if (sel == 1)
                        Kg[((size_t)(b * NH + h) * Lseq + ls) * HD + d] = f2bf(v);
                    else  // V transposed: Vt[bh][d][kv]
                        Vg[((size_t)(b * NH + h) * HD + d) * Lseq + ls] = f2bf(v);
                } else {
                    Cf[(size_t)gm * OUTD + gn] = v;
                }
            }
        }
    }
}

// ---------------------------------------------------------------- causal flash attention
// R21-verified body + diagonal-only masking: for tile pt with nblk=pt+1
// kv-blocks, only block j==nblk-1 intersects the diagonal (cols of earlier
// blocks are all <= q0-1 < row), so the 64 mask VALU ops per iter are skipped
// via a wave-uniform branch on all non-diagonal blocks. Bit-identical output.
__global__ __launch_bounds__(256) void attn_causal(
    const unsigned short* __restrict__ Qg, const unsigned short* __restrict__ Kg,
    const unsigned short* __restrict__ Vt, unsigned short* __restrict__ Og) {
    __shared__ unsigned short Kl[64 * 64];        // 8 KB, swizzled rows
    __shared__ unsigned short Vl[64 * 64];        // 8 KB, swizzled rows
    __shared__ unsigned short Pl[4][16 * 72];     // per-wave P tile (9 KB)
    int tid = threadIdx.x, wave = tid >> 6, lane = tid & 63;
    int bid = blockIdx.x;
    int xcd = bid & 7, slot = bid >> 3;       // slot 0..127
    int p = slot & 15;                        // pair index 0..15
    int bh = ((slot >> 4) << 3) | xcd;        // bh in 0..63, bh%8==xcd
    int b = bh >> 4, h = bh & 15;
    const unsigned short* Qp = Qg + (size_t)bh * Lseq * HD;
    const unsigned short* Kp = Kg + (size_t)bh * Lseq * HD;
    const unsigned short* Vp = Vt + (size_t)bh * HD * Lseq;   // [d][kv]
    int cl = lane & 15, kq = (lane >> 4) * 8, rb = (lane >> 4) * 4;
    unsigned short* Pw = &Pl[wave][0];

    int srow = tid >> 2;                      // staging row 0..63
    int sc0 = (tid & 3) * 16;                 // element chunk base
    int ssw = (srow & 7) << 3;                // write-side swizzle (elements)

    bh8 ones;
#pragma unroll
    for (int i = 0; i < 8; ++i) ones[i] = (short)0x3F80;   // bf16 1.0

    for (int pass = 0; pass < 2; ++pass) {
        int pt = pass ? (31 - p) : p;
        int q0 = pt * 64 + wave * 16;         // this wave's 16 rows

        bh8 qf0 = *(const bh8*)(Qp + (size_t)(q0 + cl) * HD + kq);
        bh8 qf1 = *(const bh8*)(Qp + (size_t)(q0 + cl) * HD + 32 + kq);

        f32x4 o[4] = {};
        f32x4 osum = {};                      // P row-sums via ones-MFMA

        int nblk = pt + 1;                    // uniform across waves
        for (int j = 0; j < nblk; ++j) {
            int kv0 = j * 64;
            bool masked = (j == nblk - 1);    // only diagonal block needs mask
            const unsigned short* Ks = Kp + (size_t)(kv0 + srow) * HD;
            const unsigned short* Vs = Vp + (size_t)srow * Lseq + kv0;
            bh8 k0 = *(const bh8*)(Ks + sc0);
            bh8 k1 = *(const bh8*)(Ks + sc0 + 8);
            bh8 v0 = *(const bh8*)(Vs + sc0);
            bh8 v1 = *(const bh8*)(Vs + sc0 + 8);
            __syncthreads();                  // prior iter's frag reads done
            *(bh8*)(Kl + srow * 64 + (sc0 ^ ssw)) = k0;
            *(bh8*)(Kl + srow * 64 + ((sc0 + 8) ^ ssw)) = k1;
            *(bh8*)(Vl + srow * 64 + (sc0 ^ ssw)) = v0;
            *(bh8*)(Vl + srow * 64 + ((sc0 + 8) ^ ssw)) = v1;
            __syncthreads();
            __builtin_amdgcn_s_setprio(1);    // T5: compute region priority
            // ---- QK^T from LDS
#pragma unroll
            for (int nb = 0; nb < 4; ++nb) {
                int row = nb * 16 + cl, rs = (row & 7) << 3;
                bh8 kf0 = *(const bh8*)(Kl + row * 64 + (kq ^ rs));
                bh8 kf1 = *(const bh8*)(Kl + row * 64 + ((kq + 32) ^ rs));
                f32x4 s = {};
                s = __builtin_amdgcn_mfma_f32_16x16x32_bf16(qf0, kf0, s, 0, 0, 0);
                s = __builtin_amdgcn_mfma_f32_16x16x32_bf16(qf1, kf1, s, 0, 0, 0);
                if (masked) {                 // wave-uniform branch
                    int col = kv0 + nb * 16 + cl;
#pragma unroll
                    for (int r = 0; r < 4; ++r) {
                        float v = s[r];                   // Q pre-scaled by 1/8
                        if (col > q0 + rb + r) v = -3e30f;
                        Pw[(rb + r) * 72 + nb * 16 + cl] = f2bf(__expf(v));
                    }
                } else {
#pragma unroll
                    for (int r = 0; r < 4; ++r)
                        Pw[(rb + r) * 72 + nb * 16 + cl] = f2bf(__expf(s[r]));
                }
            }
            // ---- P·V from LDS
            bh8 pa0 = *(const bh8*)(Pw + cl * 72 + kq);
            bh8 pa1 = *(const bh8*)(Pw + cl * 72 + 32 + kq);
#pragma unroll
            for (int db = 0; db < 4; ++db) {
                int dr = db * 16 + cl, ds = (dr & 7) << 3;
                bh8 vf0 = *(const bh8*)(Vl + dr * 64 + (kq ^ ds));
                bh8 vf1 = *(const bh8*)(Vl + dr * 64 + ((kq + 32) ^ ds));
                o[db] = __builtin_amdgcn_mfma_f32_16x16x32_bf16(pa0, vf0, o[db], 0, 0, 0);
                o[db] = __builtin_amdgcn_mfma_f32_16x16x32_bf16(pa1, vf1, o[db], 0, 0, 0);
            }
            osum = __builtin_amdgcn_mfma_f32_16x16x32_bf16(pa0, ones, osum, 0, 0, 0);
            osum = __builtin_amdgcn_mfma_f32_16x16x32_bf16(pa1, ones, osum, 0, 0, 0);
            __builtin_amdgcn_s_setprio(0);    // back to staging priority
        }
#pragma unroll
        for (int r = 0; r < 4; ++r) {
            float inv = 1.0f / osum[r];
            int row = q0 + rb + r;
            size_t obase = (size_t)(b * Lseq + row) * OUTD + h * HD;
#pragma unroll
            for (int db = 0; db < 4; ++db)
                Og[obase + db * 16 + cl] = f2bf(o[db][r] * inv);
        }
    }
}

// ---------------------------------------------------------------- launch
extern "C" void kernel_launch(void* const* d_in, const int* in_sizes, int n_in,
                              void* d_out, int out_size, void* d_ws, size_t ws_size,
                              hipStream_t stream) {
    (void)in_sizes; (void)n_in; (void)out_size; (void)ws_size;
    const float* X    = (const float*)d_in[0];
    const float* Wqkv = (const float*)d_in[1];
    const float* Wout = (const float*)d_in[2];
    float* out = (float*)d_out;

    char* ws = (char*)d_ws;
    size_t off = 0;
    unsigned short* Xb    = (unsigned short*)(ws + off); off += (size_t)Mrows * INDIM * 2;
    unsigned short* WqkvT = (unsigned short*)(ws + off); off += (size_t)QKVN * INDIM * 2;
    unsigned short* WoutT = (unsigned short*)(ws + off); off += (size_t)OUTD * (NH * HD) * 2;
    unsigned short* Qg    = (unsigned short*)(ws + off); off += (size_t)Mrows * NH * HD * 2;
    unsigned short* Kg    = (unsigned short*)(ws + off); off += (size_t)Mrows * NH * HD * 2;
    unsigned short* Vtg   = (unsigned short*)(ws + off); off += (size_t)Mrows * NH * HD * 2;
    unsigned short* Ob    = (unsigned short*)(ws + off); off += (size_t)Mrows * NH * HD * 2;

    prep_fused<<<CV_BLKS + TQ_BLKS + TO_BLKS, 256, 0, stream>>>(
        X, Xb, Wqkv, WqkvT, Wout, WoutT);
    gemm_bt<0><<<(Mrows / 128) * (QKVN / 128), 256, 0, stream>>>(
        Xb, WqkvT, nullptr, Qg, Kg, Vtg, INDIM, QKVN / 128,
        (Mrows / 128) * (QKVN / 128) / 8);
    attn_causal<<<Bsz * NH * 16, 256, 0, stream>>>(Qg, Kg, Vtg, Ob);
    gemm_bt<1><<<(Mrows / 128) * (OUTD / 128), 256, 0, stream>>>(
        Ob, WoutT, out, nullptr, nullptr, nullptr, NH * HD, OUTD / 128,
        (Mrows / 128) * (OUTD / 128) / 8);
}